// Round 1
// 251.801 us; speedup vs baseline: 1.0575x; 1.0575x over previous
//
#include <hip/hip_runtime.h>
#include <stdint.h>

namespace {
constexpr int N_   = 1024;
constexpr int BND_ = 4;
constexpr int WP_  = N_ + 2 * BND_;   // 1032
constexpr int NN_  = N_ * N_;         // 1<<20

// Tile geometry: each 512-thread block computes a 128x32 pixel tile.
constexpr int TW_ = 128;
constexpr int TH_ = 32;
// Staged LDS window. Origin is the tile origin minus HALO, CLAMPED into the
// image so every tile can use the async global->LDS fast path. Pixels whose
// sample point leaves the staged window (border tiles sampling the pad
// region, or |v| > ~7 tails) fall back to the exact global clip/pad path.
constexpr int CW_ = 148;              // 37 float4 per row; LDS addr == 16*e (linear)
constexpr int CH_ = 48;
constexpr int HALO_ = 8;
constexpr int TILES_X = N_ / TW_;     // 8
constexpr int TILES_PER_IMG = TILES_X * (N_ / TH_);  // 256
constexpr int NV_ = (CW_ / 4) * CH_;  // 1776 16-byte chunks

// Exact replication of reference gather (rare fallback): clip flat index into
// padded (WP x WP) sdf, then pad value 1.0 or interior grid value.
__device__ __forceinline__ float fetch_pad(const float* __restrict__ gb, int idx) {
    idx = min(max(idx, 0), WP_ * WP_ - 1);
    int yy = idx / WP_;
    int xx = idx - yy * WP_;
    if (xx >= BND_ && xx < WP_ - BND_ && yy >= BND_ && yy < WP_ - BND_)
        return gb[(yy - BND_) * N_ + (xx - BND_)];
    return 1.0f;
}

// Async global->LDS 16B copy. LDS destination is wave-uniform base + lane*16;
// our staging layout is linear in the element index, so consecutive lanes'
// pointers are exactly base+lane*16. Generic->AS casts via integer round-trip
// (LDS aperture is 2^32-aligned, low 32 bits of a generic LDS pointer are the
// LDS offset).
__device__ __forceinline__ void gload_lds16(const float* g, float* l) {
    __builtin_amdgcn_global_load_lds(
        (const __attribute__((address_space(1))) void*)(uintptr_t)g,
        (__attribute__((address_space(3))) void*)(uint32_t)(uintptr_t)l,
        16, 0, 0);
}
} // namespace

__global__ __launch_bounds__(512) void advect_kernel(
    const float* __restrict__ grid,   // (B,N,N) fp32
    const float* __restrict__ vec,    // (B,N,N,2) fp32
    float* __restrict__ out)          // (B,N,N) fp32
{
    __shared__ float sg[CW_ * CH_];   // 28416 B

    int bid = blockIdx.x;
    int b   = bid >> 8;               // / TILES_PER_IMG (256)
    int t   = bid & 255;
    int tyi = t >> 3;                 // / TILES_X
    int txi = t & 7;
    int it  = txi * TW_;              // tile origin (pixel coords)
    int jt  = tyi * TH_;

    // Clamped staged-window origin (grid coords). Interior tiles: it-8 / jt-8
    // (16B-aligned). Border tiles: clamped to 0 or N-CW/N-CH (also 16B-aligned:
    // 876*4 and 976*1024*4 are multiples of 16).
    int gi0 = min(max(it - HALO_, 0), N_ - CW_);
    int gj0 = min(max(jt - HALO_, 0), N_ - CH_);

    const float* gb = grid + (size_t)b * NN_;
    int tid = threadIdx.x;
    int lx0 = tid & 31;               // lane x within 32-col group
    int rr  = tid >> 5;               // row 0..15

    // ---- Issue async global->LDS staging FIRST (fire-and-forget, no VGPRs) ----
    {
        const float* src0 = gb + (size_t)gj0 * N_ + gi0;
#pragma unroll
        for (int u = 0; u < 4; ++u) {
            int e = tid + u * 512;
            if (e < NV_) {                      // u<3 always true; u==3: tid<240
                int r  = e / (CW_ / 4);
                int c4 = e - r * (CW_ / 4);
                gload_lds16(src0 + r * N_ + 4 * c4, &sg[4 * e]);
            }
        }
    }

    // ---- Prefetch this thread's 8 displacement vectors ----
    float2 pv[8];
#pragma unroll
    for (int s = 0; s < 2; ++s) {
        int j = jt + rr + 16 * s;
        const float2* vrow = reinterpret_cast<const float2*>(vec) + ((size_t)b * NN_ + (size_t)j * N_);
#pragma unroll
        for (int k = 0; k < 4; ++k)
            pv[s * 4 + k] = vrow[it + lx0 + 32 * k];
    }
    // Pin pv in registers: the previous build's VGPR_Count=20 shows the
    // compiler sank these loads past the barrier (legal: const data) and
    // re-issued them serially inside the compute loop. The empty asm makes
    // the loaded values live here, so they stay resident across the barrier.
#pragma unroll
    for (int q = 0; q < 8; ++q)
        asm volatile("" : "+v"(pv[q].x), "+v"(pv[q].y));

    __syncthreads();   // emits s_waitcnt vmcnt(0) -> drains the staging DMAs

    // ---- Compute 8 pixels per thread: cols lx0+32k, rows rr+16s ----
#pragma unroll
    for (int s = 0; s < 2; ++s) {
        int j = jt + rr + 16 * s;
        size_t rowbase = (size_t)b * NN_ + (size_t)j * N_;
#pragma unroll
        for (int k = 0; k < 4; ++k) {
            int i = it + lx0 + 32 * k;
            float vx = pv[s * 4 + k].x;
            float vy = pv[s * 4 + k].y;
            // fp32 op order must match numpy: ((i+0.5) - vx) + 3.5
            float px = ((float)i + 0.5f - vx) + 3.5f;
            float py = ((float)j + 0.5f - vy) + 3.5f;
            int x = (int)px;          // trunc toward zero == astype(int32)
            int y = (int)py;
            float fx = px - (float)x;
            float fy = py - (float)y;

            int lx = (x - BND_) - gi0;
            int ly = (y - BND_) - gj0;

            float g00, g01, g10, g11;
            if (lx >= 0 && lx <= CW_ - 2 && ly >= 0 && ly <= CH_ - 2) {
                const float* p = &sg[ly * CW_ + lx];
                g00 = p[0];
                g01 = p[1];
                g10 = p[CW_];
                g11 = p[CW_ + 1];
            } else {
                int idx = x + y * WP_;
                g00 = fetch_pad(gb, idx);
                g01 = fetch_pad(gb, idx + 1);
                g10 = fetch_pad(gb, idx + WP_);
                g11 = fetch_pad(gb, idx + WP_ + 1);
            }
            out[rowbase + i] = g00 * (1.0f - fx) * (1.0f - fy)
                             + g01 * fx          * (1.0f - fy)
                             + g10 * (1.0f - fx) * fy
                             + g11 * fx          * fy;
        }
    }
}

extern "C" void kernel_launch(void* const* d_in, const int* in_sizes, int n_in,
                              void* d_out, int out_size, void* d_ws, size_t ws_size,
                              hipStream_t stream)
{
    const float* grid = (const float*)d_in[0];
    const float* vec  = (const float*)d_in[1];
    float* out = (float*)d_out;

    int total  = in_sizes[0];                     // B*N*N
    int nB     = total / NN_;                     // 16
    int blocks = nB * TILES_PER_IMG;              // 4096
    advect_kernel<<<blocks, 512, 0, stream>>>(grid, vec, out);
}